// Round 3
// baseline (23.379 us; speedup 1.0000x reference)
//
#include <hip/hip_runtime.h>
#include <math.h>

// B=256, T=512, D_IN=64, HID=64, NB=10, NCLS=2
// Output depends ONLY on x[:, T-1, :] (lift of other timesteps is dead code).
#define BB    256
#define TT    512
#define DIN   64
#define HIDD  64
#define NBAS  10
#define NCLS  2

#define NTHR   1024
#define NWAVES 16
#define NPHI   (DIN * NBAS)           // 640 (i,k) pairs per layer
#define EPT    (NPHI / NWAVES)        // 40 terms per wave (= 4 in-channels x 10 bases)

__global__ __launch_bounds__(NTHR, 4) void kan_fwd(
    const float* __restrict__ x,
    const float* __restrict__ lift_c, const float* __restrict__ lift_w, const float* __restrict__ lift_coef,
    const float* __restrict__ rnn_c,  const float* __restrict__ rnn_w,  const float* __restrict__ rnn_coef,
    const float* __restrict__ head_c, const float* __restrict__ head_w, const float* __restrict__ head_coef,
    const float* __restrict__ W, const float* __restrict__ bvec,
    float* __restrict__ out)
{
    const int b = blockIdx.x;    // sample
    const int t = threadIdx.x;
    const int o = t & 63;        // lane = output channel this thread accumulates
    const int w = t >> 6;        // wave id 0..15 -> slice of 40 (i,k) terms

    __shared__ float act[DIN];           // current activation vector
    __shared__ float part[NWAVES][DIN];  // per-wave partial sums

    // ---- issue ALL independent global loads up front (static addresses) ----
    float xv = 0.0f;
    if (t < DIN) xv = x[((size_t)b * TT + (TT - 1)) * DIN + t];

    // per-lane basis params: lane l -> (li = l/10, lk = l%10); lk<10 for all l<64
    const int li = o / NBAS;
    const int lk = o - li * NBAS;
    const float lc = lift_c[lk], liw = 1.0f / lift_w[lk];
    const float rc = rnn_c[lk],  riw = 1.0f / rnn_w[lk];
    const float hc = head_c[lk], hiw = 1.0f / head_w[lk];
    float W0 = 0.0f, W1 = 0.0f;
    if (t < DIN) { W0 = W[t * NCLS + 0]; W1 = W[t * NCLS + 1]; }

    const int e0 = w * EPT;
    const float* cpA = lift_coef + (size_t)e0 * HIDD + o;
    const float* cpB = rnn_coef  + (size_t)e0 * HIDD + o;
    const float* cpC = head_coef + (size_t)e0 * HIDD + o;

    float cA[EPT], cB[EPT];              // layer-1/2 coeffs prefetched to VGPRs
    #pragma unroll
    for (int e = 0; e < EPT; ++e) cA[e] = cpA[e * HIDD];
    #pragma unroll
    for (int e = 0; e < EPT; ++e) cB[e] = cpB[e * HIDD];

    if (t < DIN) act[t] = xv;
    __syncthreads();

    // contraction: acc_o = sum_e phi[e] * coeff[e][o]; phi broadcast via readlane
    auto contract = [&](float pv, const float (&cr)[EPT]) -> float {
        float a0 = 0.0f, a1 = 0.0f;
        #pragma unroll
        for (int e = 0; e < EPT; e += 2) {
            a0 = fmaf(__shfl(pv, e),     cr[e],     a0);
            a1 = fmaf(__shfl(pv, e + 1), cr[e + 1], a1);
        }
        return a0 + a1;
    };

    // ---------------- layer 1: z = lift(x_last), no sigmoid ----------------
    float pv = 0.0f;
    if (o < EPT) pv = tanhf((act[(w << 2) + li] - lc) * liw);
    // issue layer-3 coeff loads now; they overlap layers 1-2 compute
    float cC[EPT];
    #pragma unroll
    for (int e = 0; e < EPT; ++e) cC[e] = cpC[e * HIDD];

    part[w][o] = contract(pv, cA);
    __syncthreads();
    if (t < DIN) {
        float s = 0.0f;
        #pragma unroll
        for (int ww = 0; ww < NWAVES; ++ww) s += part[ww][t];
        act[t] = s;
    }
    __syncthreads();

    // ---------------- layer 2: h = sigmoid(rnn(z)) ----------------
    pv = 0.0f;
    if (o < EPT) pv = tanhf((act[(w << 2) + li] - rc) * riw);
    part[w][o] = contract(pv, cB);
    __syncthreads();
    if (t < DIN) {
        float s = 0.0f;
        #pragma unroll
        for (int ww = 0; ww < NWAVES; ++ww) s += part[ww][t];
        act[t] = 1.0f / (1.0f + expf(-s));
    }
    __syncthreads();

    // ---------------- layer 3: phi = sigmoid(head(h)) + linear head ----------------
    pv = 0.0f;
    if (o < EPT) pv = tanhf((act[(w << 2) + li] - hc) * hiw);
    part[w][o] = contract(pv, cC);
    __syncthreads();
    if (t < DIN) {   // t<64 == wave 0: finish entirely in-register
        float s = 0.0f;
        #pragma unroll
        for (int ww = 0; ww < NWAVES; ++ww) s += part[ww][t];
        s = 1.0f / (1.0f + expf(-s));
        float p0 = s * W0;
        float p1 = s * W1;
        #pragma unroll
        for (int off = 32; off > 0; off >>= 1) {
            p0 += __shfl_down(p0, off);
            p1 += __shfl_down(p1, off);
        }
        if (t == 0) {
            out[b * NCLS + 0] = p0 + bvec[0];
            out[b * NCLS + 1] = p1 + bvec[1];
        }
    }
}

extern "C" void kernel_launch(void* const* d_in, const int* in_sizes, int n_in,
                              void* d_out, int out_size, void* d_ws, size_t ws_size,
                              hipStream_t stream) {
    const float* x          = (const float*)d_in[0];
    const float* lift_c     = (const float*)d_in[1];
    const float* lift_w     = (const float*)d_in[2];
    const float* lift_coef  = (const float*)d_in[3];
    const float* rnn_c      = (const float*)d_in[4];
    const float* rnn_w      = (const float*)d_in[5];
    const float* rnn_coef   = (const float*)d_in[6];
    const float* head_c     = (const float*)d_in[7];
    const float* head_w     = (const float*)d_in[8];
    const float* head_coef  = (const float*)d_in[9];
    const float* W          = (const float*)d_in[10];
    const float* bvec       = (const float*)d_in[11];
    float* out              = (float*)d_out;

    kan_fwd<<<dim3(BB), dim3(NTHR), 0, stream>>>(
        x, lift_c, lift_w, lift_coef,
        rnn_c, rnn_w, rnn_coef,
        head_c, head_w, head_coef,
        W, bvec, out);
}

// Round 4
// 21.410 us; speedup vs baseline: 1.0920x; 1.0920x over previous
//
#include <hip/hip_runtime.h>
#include <math.h>

// B=256, T=512, D_IN=64, HID=64, NB=10, NCLS=2
// Output depends ONLY on x[:, T-1, :] (lift of other timesteps is dead code).
#define BB    256
#define TT    512
#define DIN   64
#define HIDD  64
#define NBAS  10
#define NCLS  2

#define NTHR   1024
#define NWAVES 16
#define NPHI   (DIN * NBAS)           // 640 (i,k) pairs per layer
#define EPT    (NPHI / NWAVES)        // 40 terms per wave (4 in-channels x 10 bases)
#define NF4    (EPT / 4)              // 10 float4 loads per wave per layer

__global__ __launch_bounds__(NTHR) void kan_fwd(
    const float* __restrict__ x,
    const float* __restrict__ lift_c, const float* __restrict__ lift_w, const float* __restrict__ lift_coef,
    const float* __restrict__ rnn_c,  const float* __restrict__ rnn_w,  const float* __restrict__ rnn_coef,
    const float* __restrict__ head_c, const float* __restrict__ head_w, const float* __restrict__ head_coef,
    const float* __restrict__ W, const float* __restrict__ bvec,
    float* __restrict__ out)
{
    const int b = blockIdx.x;     // sample
    const int t = threadIdx.x;
    const int l = t & 63;         // lane
    const int w = t >> 6;         // wave id 0..15 -> e-slice [w*40, w*40+40)

    // float4 load mapping: lane l covers e-subrow (l>>4) and channels og..og+3
    const int esub = l >> 4;            // 0..3
    const int og   = (l & 15) << 2;     // 0,4,...,60
    const int e0   = w * EPT;

    __shared__ float act[DIN];            // current activation vector
    __shared__ float part[NWAVES][DIN];   // per-wave partial sums

    // ---- independent loads issued up front ----
    float xv = 0.0f;
    if (t < DIN) xv = x[((size_t)b * TT + (TT - 1)) * DIN + t];

    // per-lane basis params for phi lanes (p = l in 0..39 -> i = w*4 + p/10, k = p%10)
    const int pi = l / NBAS;            // 0..6 (only <4 used when l<40)
    const int pk = l - pi * NBAS;       // 0..9
    const float lc = lift_c[pk], liw = 1.0f / lift_w[pk];
    const float rc = rnn_c[pk],  riw = 1.0f / rnn_w[pk];
    const float hc = head_c[pk], hiw = 1.0f / head_w[pk];
    float W0 = 0.0f, W1 = 0.0f;
    if (t < DIN) { W0 = W[t * NCLS + 0]; W1 = W[t * NCLS + 1]; }

    // float4 views of the coeff rows this lane loads: element e = e0+esub+4j,
    // float4 index = (e*HIDD + og)/4 = e*16 + (og>>2), j-stride = 64 float4s.
    const float4* fA = (const float4*)lift_coef + (size_t)(e0 + esub) * 16 + (og >> 2);
    const float4* fB = (const float4*)rnn_coef  + (size_t)(e0 + esub) * 16 + (og >> 2);
    const float4* fC = (const float4*)head_coef + (size_t)(e0 + esub) * 16 + (og >> 2);

    float4 c1[NF4], c2[NF4], c3[NF4];
    #pragma unroll
    for (int j = 0; j < NF4; ++j) c1[j] = fA[j * 64];   // layer-1 chunk
    #pragma unroll
    for (int j = 0; j < NF4; ++j) c2[j] = fB[j * 64];   // layer-2 chunk (in flight)

    if (t < DIN) act[t] = xv;
    __syncthreads();

    // contraction for this lane's 4 channels; phi broadcast via variable-lane shfl
    auto contract = [&](float pv, const float4 (&cf)[NF4]) -> float4 {
        float4 a = make_float4(0.f, 0.f, 0.f, 0.f);
        #pragma unroll
        for (int j = 0; j < NF4; ++j) {
            const float pj = __shfl(pv, esub + 4 * j);
            a.x = fmaf(pj, cf[j].x, a.x);
            a.y = fmaf(pj, cf[j].y, a.y);
            a.z = fmaf(pj, cf[j].z, a.z);
            a.w = fmaf(pj, cf[j].w, a.w);
        }
        return a;
    };
    auto xreduce = [&](float4 a) -> float4 {
        #pragma unroll
        for (int off = 16; off < 64; off <<= 1) {
            a.x += __shfl_xor(a.x, off);
            a.y += __shfl_xor(a.y, off);
            a.z += __shfl_xor(a.z, off);
            a.w += __shfl_xor(a.w, off);
        }
        return a;   // every lane now holds the wave-sum for channels og..og+3
    };

    // ---------------- layer 1: z = lift(x_last), no sigmoid ----------------
    float pv = 0.0f;
    if (l < EPT) pv = tanhf((act[(w << 2) + pi] - lc) * liw);
    float4 a = contract(pv, c1);
    #pragma unroll
    for (int j = 0; j < NF4; ++j) c3[j] = fC[j * 64];   // layer-3 chunk (c1 regs dead)
    a = xreduce(a);
    if (esub == 0) *(float4*)&part[w][og] = a;
    __syncthreads();
    if (t < DIN) {
        float s = 0.0f;
        #pragma unroll
        for (int ww = 0; ww < NWAVES; ++ww) s += part[ww][t];
        act[t] = s;
    }
    __syncthreads();

    // ---------------- layer 2: h = sigmoid(rnn(z)) ----------------
    pv = 0.0f;
    if (l < EPT) pv = tanhf((act[(w << 2) + pi] - rc) * riw);
    a = xreduce(contract(pv, c2));
    if (esub == 0) *(float4*)&part[w][og] = a;
    __syncthreads();
    if (t < DIN) {
        float s = 0.0f;
        #pragma unroll
        for (int ww = 0; ww < NWAVES; ++ww) s += part[ww][t];
        act[t] = 1.0f / (1.0f + expf(-s));
    }
    __syncthreads();

    // ---------------- layer 3: phi = sigmoid(head(h)) + linear head ----------------
    pv = 0.0f;
    if (l < EPT) pv = tanhf((act[(w << 2) + pi] - hc) * hiw);
    a = xreduce(contract(pv, c3));
    if (esub == 0) *(float4*)&part[w][og] = a;
    __syncthreads();
    if (t < DIN) {     // wave 0 finishes in-register
        float s = 0.0f;
        #pragma unroll
        for (int ww = 0; ww < NWAVES; ++ww) s += part[ww][t];
        s = 1.0f / (1.0f + expf(-s));
        float p0 = s * W0;
        float p1 = s * W1;
        #pragma unroll
        for (int off = 32; off > 0; off >>= 1) {
            p0 += __shfl_down(p0, off);
            p1 += __shfl_down(p1, off);
        }
        if (t == 0) {
            out[b * NCLS + 0] = p0 + bvec[0];
            out[b * NCLS + 1] = p1 + bvec[1];
        }
    }
}

extern "C" void kernel_launch(void* const* d_in, const int* in_sizes, int n_in,
                              void* d_out, int out_size, void* d_ws, size_t ws_size,
                              hipStream_t stream) {
    const float* x          = (const float*)d_in[0];
    const float* lift_c     = (const float*)d_in[1];
    const float* lift_w     = (const float*)d_in[2];
    const float* lift_coef  = (const float*)d_in[3];
    const float* rnn_c      = (const float*)d_in[4];
    const float* rnn_w      = (const float*)d_in[5];
    const float* rnn_coef   = (const float*)d_in[6];
    const float* head_c     = (const float*)d_in[7];
    const float* head_w     = (const float*)d_in[8];
    const float* head_coef  = (const float*)d_in[9];
    const float* W          = (const float*)d_in[10];
    const float* bvec       = (const float*)d_in[11];
    float* out              = (float*)d_out;

    kan_fwd<<<dim3(BB), dim3(NTHR), 0, stream>>>(
        x, lift_c, lift_w, lift_coef,
        rnn_c, rnn_w, rnn_coef,
        head_c, head_w, head_coef,
        W, bvec, out);
}

// Round 5
// 17.230 us; speedup vs baseline: 1.3569x; 1.2426x over previous
//
#include <hip/hip_runtime.h>
#include <math.h>

// B=256, T=512, D_IN=64, HID=64, NB=10, NCLS=2
// Output depends ONLY on x[:, T-1, :] (lift of other timesteps is dead code).
#define BB    256
#define TT    512
#define DIN   64
#define HIDD  64
#define NBAS  10
#define NCLS  2

#define G      4                    // samples per block (coeff reuse factor)
#define NBLK   (BB / G)             // 64 blocks
#define NTHR   1024
#define NWAVES 16
#define NPHI   (DIN * NBAS)         // 640 (i,k) pairs per layer
#define EPT    (NPHI / NWAVES)      // 40 e's per wave
#define NF4    (EPT / 4)            // 10 float4 coeff loads per lane per layer

__global__ __launch_bounds__(NTHR) void kan_fwd(
    const float* __restrict__ x,
    const float* __restrict__ lift_c, const float* __restrict__ lift_w, const float* __restrict__ lift_coef,
    const float* __restrict__ rnn_c,  const float* __restrict__ rnn_w,  const float* __restrict__ rnn_coef,
    const float* __restrict__ head_c, const float* __restrict__ head_w, const float* __restrict__ head_coef,
    const float* __restrict__ W, const float* __restrict__ bvec,
    float* __restrict__ out)
{
    const int b    = blockIdx.x;      // covers samples G*b .. G*b+3
    const int t    = threadIdx.x;
    const int l    = t & 63;          // lane
    const int w    = t >> 6;          // wave 0..15 -> e-slice [40w, 40w+40)
    const int esub = l >> 4;          // 0..3
    const int og   = (l & 15) << 2;   // channel group base: 0,4,...,60

    __shared__ __align__(16) float act[G][DIN];          // activations, 4 samples
    __shared__ __align__(16) float phiT[NPHI][G];        // [e][g] -> 16B rows, b128 reads
    __shared__ __align__(16) float part[NWAVES][G][DIN]; // per-wave partials (16 KB)

    // ---- load x last-timestep for the 4 samples ----
    if (t < G * DIN) {
        const int g = t >> 6, i = t & 63;
        act[g][i] = x[((size_t)(G * b + g) * TT + (TT - 1)) * DIN + i];
    }

    // ---- static per-thread phi work items: idx = t, t+1024, t+2048(<2560) ----
    const int idx0 = t, idx1 = t + NTHR, idx2 = t + 2 * NTHR;
    const int g0 = idx0 / NPHI, r0 = idx0 - g0 * NPHI, i0 = r0 / NBAS, k0 = r0 - i0 * NBAS;
    const int g1 = idx1 / NPHI, r1 = idx1 - g1 * NPHI, i1 = r1 / NBAS, k1 = r1 - i1 * NBAS;
    const int g2 = idx2 / NPHI, r2 = idx2 - g2 * NPHI, i2 = r2 / NBAS, k2 = r2 - i2 * NBAS;
    const bool has2 = (t < (G * NPHI - 2 * NTHR));   // t < 512

    // coeff float4 base: element e=(40w+esub+4j), channel og -> f4 idx e*16+og/4, j-stride 64
    const int e0 = w * EPT + esub;
    const float4* fA = (const float4*)lift_coef + (size_t)e0 * 16 + (og >> 2);
    const float4* fB = (const float4*)rnn_coef  + (size_t)e0 * 16 + (og >> 2);
    const float4* fC = (const float4*)head_coef + (size_t)e0 * 16 + (og >> 2);

    __syncthreads();   // act(x) ready

    // one KAN layer; returns this thread's final-reduce value (valid for t<256), or act-stores it
    auto layer = [&](const float* __restrict__ cptr, const float* __restrict__ wptr,
                     const float4* __restrict__ f4, bool sig, bool store_act) -> float {
        // ---- phi phase: 2560 tanh spread over all threads ----
        {
            const float c0v = cptr[k0], w0v = 1.0f / wptr[k0];
            const float c1v = cptr[k1], w1v = 1.0f / wptr[k1];
            phiT[r0][g0] = tanhf((act[g0][i0] - c0v) * w0v);
            phiT[r1][g1] = tanhf((act[g1][i1] - c1v) * w1v);
            if (has2) {
                const float c2v = cptr[k2], w2v = 1.0f / wptr[k2];
                phiT[r2][g2] = tanhf((act[g2][i2] - c2v) * w2v);
            }
        }
        __syncthreads();   // phi ready

        // ---- contraction: 10 coeff float4 + 10 phi b128 broadcasts, 160 FMA ----
        float4 acc[G];
        #pragma unroll
        for (int g = 0; g < G; ++g) acc[g] = make_float4(0.f, 0.f, 0.f, 0.f);
        #pragma unroll
        for (int j = 0; j < NF4; ++j) {
            const float4 cf = f4[j * 64];                         // coeff[e][og..og+3]
            const float4 ph = *(const float4*)&phiT[e0 + 4 * j][0];  // phi[e][0..3]
            acc[0].x = fmaf(ph.x, cf.x, acc[0].x); acc[0].y = fmaf(ph.x, cf.y, acc[0].y);
            acc[0].z = fmaf(ph.x, cf.z, acc[0].z); acc[0].w = fmaf(ph.x, cf.w, acc[0].w);
            acc[1].x = fmaf(ph.y, cf.x, acc[1].x); acc[1].y = fmaf(ph.y, cf.y, acc[1].y);
            acc[1].z = fmaf(ph.y, cf.z, acc[1].z); acc[1].w = fmaf(ph.y, cf.w, acc[1].w);
            acc[2].x = fmaf(ph.z, cf.x, acc[2].x); acc[2].y = fmaf(ph.z, cf.y, acc[2].y);
            acc[2].z = fmaf(ph.z, cf.z, acc[2].z); acc[2].w = fmaf(ph.z, cf.w, acc[2].w);
            acc[3].x = fmaf(ph.w, cf.x, acc[3].x); acc[3].y = fmaf(ph.w, cf.y, acc[3].y);
            acc[3].z = fmaf(ph.w, cf.z, acc[3].z); acc[3].w = fmaf(ph.w, cf.w, acc[3].w);
        }
        // reduce across the 4 esub groups (lanes l^16, l^32)
        #pragma unroll
        for (int off = 16; off < 64; off <<= 1) {
            #pragma unroll
            for (int g = 0; g < G; ++g) {
                acc[g].x += __shfl_xor(acc[g].x, off);
                acc[g].y += __shfl_xor(acc[g].y, off);
                acc[g].z += __shfl_xor(acc[g].z, off);
                acc[g].w += __shfl_xor(acc[g].w, off);
            }
        }
        if (esub == 0) {
            #pragma unroll
            for (int g = 0; g < G; ++g) *(float4*)&part[w][g][og] = acc[g];
        }
        __syncthreads();   // partials ready

        // ---- final reduce over 16 waves: threads 0..255 ----
        float s = 0.0f;
        if (t < G * DIN) {
            const int g = t >> 6, o = t & 63;
            #pragma unroll
            for (int ww = 0; ww < NWAVES; ++ww) s += part[ww][g][o];
            if (sig) s = 1.0f / (1.0f + expf(-s));
            if (store_act) act[g][o] = s;
        }
        __syncthreads();   // act ready / phiT+part free for reuse
        return s;
    };

    layer(lift_c, lift_w, fA, /*sig=*/false, /*store_act=*/true);   // z
    layer(rnn_c,  rnn_w,  fB, /*sig=*/true,  /*store_act=*/true);   // h
    const float s3 = layer(head_c, head_w, fC, /*sig=*/true, /*store_act=*/false); // head phi

    // ---- linear head: each of waves 0..3 handles one sample g=w ----
    if (t < G * DIN) {
        const int g = t >> 6, o = t & 63;
        float p0 = s3 * W[o * NCLS + 0];
        float p1 = s3 * W[o * NCLS + 1];
        #pragma unroll
        for (int off = 32; off > 0; off >>= 1) {
            p0 += __shfl_down(p0, off);
            p1 += __shfl_down(p1, off);
        }
        if (o == 0) {
            out[(G * b + g) * NCLS + 0] = p0 + bvec[0];
            out[(G * b + g) * NCLS + 1] = p1 + bvec[1];
        }
    }
}

extern "C" void kernel_launch(void* const* d_in, const int* in_sizes, int n_in,
                              void* d_out, int out_size, void* d_ws, size_t ws_size,
                              hipStream_t stream) {
    const float* x          = (const float*)d_in[0];
    const float* lift_c     = (const float*)d_in[1];
    const float* lift_w     = (const float*)d_in[2];
    const float* lift_coef  = (const float*)d_in[3];
    const float* rnn_c      = (const float*)d_in[4];
    const float* rnn_w      = (const float*)d_in[5];
    const float* rnn_coef   = (const float*)d_in[6];
    const float* head_c     = (const float*)d_in[7];
    const float* head_w     = (const float*)d_in[8];
    const float* head_coef  = (const float*)d_in[9];
    const float* W          = (const float*)d_in[10];
    const float* bvec       = (const float*)d_in[11];
    float* out              = (float*)d_out;

    kan_fwd<<<dim3(NBLK), dim3(NTHR), 0, stream>>>(
        x, lift_c, lift_w, lift_coef,
        rnn_c, rnn_w, rnn_coef,
        head_c, head_w, head_coef,
        W, bvec, out);
}

// Round 6
// 13.690 us; speedup vs baseline: 1.7078x; 1.2586x over previous
//
#include <hip/hip_runtime.h>
#include <math.h>

// B=256, T=512, D_IN=64, HID=64, NB=10, NCLS=2
// Output depends ONLY on x[:, T-1, :] (lift of other timesteps is dead code).
#define BB    256
#define TT    512
#define DIN   64
#define HIDD  64
#define NBAS  10
#define NCLS  2

#define NTHR  256                 // 4 waves; grid=256 -> 1 block/CU -> 1 wave/SIMD
#define NW    4
#define EPW   160                 // e-terms per wave (e = i*NB + k, 640 total)
#define NF4   40                  // float4 coeff loads per lane per layer

__device__ __forceinline__ float sigmoidf_(float v) {
    return 1.0f / (1.0f + expf(-v));
}

__global__ __launch_bounds__(NTHR, 1) void kan_fwd(
    const float* __restrict__ x,
    const float* __restrict__ lift_c, const float* __restrict__ lift_w, const float* __restrict__ lift_coef,
    const float* __restrict__ rnn_c,  const float* __restrict__ rnn_w,  const float* __restrict__ rnn_coef,
    const float* __restrict__ head_c, const float* __restrict__ head_w, const float* __restrict__ head_coef,
    const float* __restrict__ W, const float* __restrict__ bvec,
    float* __restrict__ out)
{
    const int b    = blockIdx.x;      // sample
    const int t    = threadIdx.x;
    const int l    = t & 63;          // lane
    const int w    = t >> 6;          // wave 0..3 -> e-slice [160w, 160w+160)
    const int esub = l >> 4;          // 0..3
    const int og   = (l & 15) << 2;   // channel group: 0,4,...,60

    __shared__ float act[DIN];
    __shared__ __align__(16) float part[NW][DIN];

    // phi work items per lane: e = 160w + {l, 64+l, 128+l(l<32)}
    const int i0 = (w << 4) + l / NBAS,          k0 = l % NBAS;
    const int i1 = (w << 4) + (64 + l) / NBAS,   k1 = (64 + l) % NBAS;
    const int i2 = (w << 4) + (128 + l) / NBAS,  k2 = (128 + l) % NBAS;

    // layer-1 phi inputs straight from x (no act staging, no initial barrier)
    const float* xb = x + ((size_t)b * TT + (TT - 1)) * DIN;
    const float x0 = xb[i0];
    const float x1 = xb[i1];
    const float x2 = (l < 32) ? xb[i2] : 0.0f;

    // basis params (tiny, L1-hot)
    const float lc0 = lift_c[k0], lw0 = 1.0f / lift_w[k0];
    const float lc1 = lift_c[k1], lw1 = 1.0f / lift_w[k1];
    const float lc2 = lift_c[k2], lw2 = 1.0f / lift_w[k2];
    const float rc0 = rnn_c[k0],  rw0 = 1.0f / rnn_w[k0];
    const float rc1 = rnn_c[k1],  rw1 = 1.0f / rnn_w[k1];
    const float rc2 = rnn_c[k2],  rw2 = 1.0f / rnn_w[k2];
    const float hc0 = head_c[k0], hw0 = 1.0f / head_w[k0];
    const float hc1 = head_c[k1], hw1 = 1.0f / head_w[k1];
    const float hc2 = head_c[k2], hw2 = 1.0f / head_w[k2];
    float W0 = 0.0f, W1 = 0.0f;
    if (t < DIN) { W0 = W[t * NCLS + 0]; W1 = W[t * NCLS + 1]; }

    // coeff float4 bases: element e = 160w+esub+4j, channels og..og+3;
    // float4 index = e*16 + og/4, j-stride 64.
    const size_t fbase = (size_t)(EPW * w + esub) * 16 + (og >> 2);
    const float4* fA = (const float4*)lift_coef + fbase;
    const float4* fB = (const float4*)rnn_coef  + fbase;
    const float4* fC = (const float4*)head_coef + fbase;

    // phi broadcast: lane's j-th term needs phi[esub+4j] of this wave's slice
    #define CONTRACT(ACC, PV0, PV1, PV2, CARR)                                  \
        {                                                                       \
            _Pragma("unroll")                                                   \
            for (int j = 0; j < NF4; ++j) {                                     \
                float pj;                                                       \
                if (j < 16)      pj = __shfl((PV0), esub + 4 * j);              \
                else if (j < 32) pj = __shfl((PV1), esub + 4 * j - 64);         \
                else             pj = __shfl((PV2), esub + 4 * j - 128);        \
                const float4 cf = (CARR)[j];                                    \
                (ACC).x = fmaf(pj, cf.x, (ACC).x);                              \
                (ACC).y = fmaf(pj, cf.y, (ACC).y);                              \
                (ACC).z = fmaf(pj, cf.z, (ACC).z);                              \
                (ACC).w = fmaf(pj, cf.w, (ACC).w);                              \
            }                                                                   \
        }

    #define XREDUCE(ACC)                                                        \
        {                                                                       \
            _Pragma("unroll")                                                   \
            for (int off = 16; off < 64; off <<= 1) {                           \
                (ACC).x += __shfl_xor((ACC).x, off);                            \
                (ACC).y += __shfl_xor((ACC).y, off);                            \
                (ACC).z += __shfl_xor((ACC).z, off);                            \
                (ACC).w += __shfl_xor((ACC).w, off);                            \
            }                                                                   \
        }

    // ---- layer-1 coeff slice ----
    float4 c1[NF4];
    #pragma unroll
    for (int j = 0; j < NF4; ++j) c1[j] = fA[j * 64];

    // ================= layer 1: z = lift(x_last), no sigmoid =================
    float pv0 = tanhf((x0 - lc0) * lw0);
    float pv1 = tanhf((x1 - lc1) * lw1);
    float pv2 = (l < 32) ? tanhf((x2 - lc2) * lw2) : 0.0f;

    float4 a = make_float4(0.f, 0.f, 0.f, 0.f);
    CONTRACT(a, pv0, pv1, pv2, c1);

    // prefetch layer-2 slice (overlaps reduce + barrier + tanh)
    float4 c2[NF4];
    #pragma unroll
    for (int j = 0; j < NF4; ++j) c2[j] = fB[j * 64];

    XREDUCE(a);
    if (esub == 0) *(float4*)&part[w][og] = a;
    __syncthreads();
    if (t < DIN)
        act[t] = part[0][t] + part[1][t] + part[2][t] + part[3][t];
    __syncthreads();

    // ================= layer 2: h = sigmoid(rnn(z)) =================
    pv0 = tanhf((act[i0] - rc0) * rw0);
    pv1 = tanhf((act[i1] - rc1) * rw1);
    pv2 = (l < 32) ? tanhf((act[i2] - rc2) * rw2) : 0.0f;

    a = make_float4(0.f, 0.f, 0.f, 0.f);
    CONTRACT(a, pv0, pv1, pv2, c2);

    // prefetch layer-3 slice
    float4 c3[NF4];
    #pragma unroll
    for (int j = 0; j < NF4; ++j) c3[j] = fC[j * 64];

    XREDUCE(a);
    if (esub == 0) *(float4*)&part[w][og] = a;
    __syncthreads();
    if (t < DIN)
        act[t] = sigmoidf_(part[0][t] + part[1][t] + part[2][t] + part[3][t]);
    __syncthreads();

    // ================= layer 3: phi = sigmoid(head(h)) + linear head =========
    pv0 = tanhf((act[i0] - hc0) * hw0);
    pv1 = tanhf((act[i1] - hc1) * hw1);
    pv2 = (l < 32) ? tanhf((act[i2] - hc2) * hw2) : 0.0f;

    a = make_float4(0.f, 0.f, 0.f, 0.f);
    CONTRACT(a, pv0, pv1, pv2, c3);
    XREDUCE(a);
    if (esub == 0) *(float4*)&part[w][og] = a;
    __syncthreads();

    if (t < DIN) {   // wave 0 finishes in-register
        float s = part[0][t] + part[1][t] + part[2][t] + part[3][t];
        s = sigmoidf_(s);
        float p0 = s * W0;
        float p1 = s * W1;
        #pragma unroll
        for (int off = 32; off > 0; off >>= 1) {
            p0 += __shfl_down(p0, off);
            p1 += __shfl_down(p1, off);
        }
        if (t == 0) {
            out[b * NCLS + 0] = p0 + bvec[0];
            out[b * NCLS + 1] = p1 + bvec[1];
        }
    }

    #undef CONTRACT
    #undef XREDUCE
}

extern "C" void kernel_launch(void* const* d_in, const int* in_sizes, int n_in,
                              void* d_out, int out_size, void* d_ws, size_t ws_size,
                              hipStream_t stream) {
    const float* x          = (const float*)d_in[0];
    const float* lift_c     = (const float*)d_in[1];
    const float* lift_w     = (const float*)d_in[2];
    const float* lift_coef  = (const float*)d_in[3];
    const float* rnn_c      = (const float*)d_in[4];
    const float* rnn_w      = (const float*)d_in[5];
    const float* rnn_coef   = (const float*)d_in[6];
    const float* head_c     = (const float*)d_in[7];
    const float* head_w     = (const float*)d_in[8];
    const float* head_coef  = (const float*)d_in[9];
    const float* W          = (const float*)d_in[10];
    const float* bvec       = (const float*)d_in[11];
    float* out              = (float*)d_out;

    kan_fwd<<<dim3(BB), dim3(NTHR), 0, stream>>>(
        x, lift_c, lift_w, lift_coef,
        rnn_c, rnn_w, rnn_coef,
        head_c, head_w, head_coef,
        W, bvec, out);
}

// Round 7
// 13.576 us; speedup vs baseline: 1.7221x; 1.0084x over previous
//
#include <hip/hip_runtime.h>
#include <math.h>

// B=256, T=512, D_IN=64, HID=64, NB=10, NCLS=2
// Output depends ONLY on x[:, T-1, :] (lift of other timesteps is dead code).
// Structure: 256 blocks (1 sample/CU) x 512 threads (8 waves = 2/SIMD for TLP,
// VGPR cap 256 -> room for float4 coeff slices + 1-layer-ahead prefetch).
#define BB    256
#define TT    512
#define DIN   64
#define HIDD  64
#define NBAS  10
#define NCLS  2

#define NTHR  512
#define NW    8
#define EPW   80                  // e-terms per wave (e = i*NB + k, 640 total)
#define NF4   20                  // float4 coeff loads per lane per layer

__device__ __forceinline__ float sigmoidf_(float v) {
    return 1.0f / (1.0f + expf(-v));
}

__global__ __launch_bounds__(NTHR, 2) void kan_fwd(
    const float* __restrict__ x,
    const float* __restrict__ lift_c, const float* __restrict__ lift_w, const float* __restrict__ lift_coef,
    const float* __restrict__ rnn_c,  const float* __restrict__ rnn_w,  const float* __restrict__ rnn_coef,
    const float* __restrict__ head_c, const float* __restrict__ head_w, const float* __restrict__ head_coef,
    const float* __restrict__ W, const float* __restrict__ bvec,
    float* __restrict__ out)
{
    const int b    = blockIdx.x;      // sample
    const int t    = threadIdx.x;
    const int l    = t & 63;          // lane
    const int w    = t >> 6;          // wave 0..7 -> e-slice [80w, 80w+80)
    const int esub = l >> 4;          // 0..3
    const int og   = (l & 15) << 2;   // channel group: 0,4,...,60

    __shared__ float act[DIN];
    __shared__ __align__(16) float part[NW][DIN];

    // phi work items: wave w covers e = 80w + {l  (all lanes), 64+l (l<16)}
    // e/NBAS = 8w + (local)/10 exactly (80w divisible by 10).
    const int i0 = (w << 3) + l / NBAS,        k0 = l % NBAS;
    const int i1 = (w << 3) + (64 + l) / NBAS, k1 = (64 + l) % NBAS;
    const bool ph1 = (l < (EPW - 64));   // lanes 0..15 carry the second phi

    // layer-1 phi inputs straight from x (no act staging, no initial barrier)
    const float* xb = x + ((size_t)b * TT + (TT - 1)) * DIN;
    const float x0 = xb[i0];
    const float x1 = ph1 ? xb[i1] : 0.0f;

    // basis params (tiny, L1-hot)
    const float lc0 = lift_c[k0], lw0 = 1.0f / lift_w[k0];
    const float lc1 = lift_c[k1], lw1 = 1.0f / lift_w[k1];
    const float rc0 = rnn_c[k0],  rw0 = 1.0f / rnn_w[k0];
    const float rc1 = rnn_c[k1],  rw1 = 1.0f / rnn_w[k1];
    const float hc0 = head_c[k0], hw0 = 1.0f / head_w[k0];
    const float hc1 = head_c[k1], hw1 = 1.0f / head_w[k1];
    float W0 = 0.0f, W1 = 0.0f;
    if (t < DIN) { W0 = W[t * NCLS + 0]; W1 = W[t * NCLS + 1]; }

    // coeff float4 base: element e = 80w+esub+4j, channels og..og+3;
    // float4 index = e*16 + og/4, j-stride 64 float4s.
    const size_t fbase = (size_t)(EPW * w + esub) * 16 + (og >> 2);
    const float4* fA = (const float4*)lift_coef + fbase;
    const float4* fB = (const float4*)rnn_coef  + fbase;
    const float4* fC = (const float4*)head_coef + fbase;

    // j<16 -> phi local idx esub+4j < 64 (pv0); j>=16 -> pv1 lane esub+4(j-16)
    #define CONTRACT(ACC, PV0, PV1, CARR)                                       \
        {                                                                       \
            _Pragma("unroll")                                                   \
            for (int j = 0; j < NF4; ++j) {                                     \
                const float pj = (j < 16) ? __shfl((PV0), esub + 4 * j)         \
                                          : __shfl((PV1), esub + 4 * (j - 16)); \
                const float4 cf = (CARR)[j];                                    \
                (ACC).x = fmaf(pj, cf.x, (ACC).x);                              \
                (ACC).y = fmaf(pj, cf.y, (ACC).y);                              \
                (ACC).z = fmaf(pj, cf.z, (ACC).z);                              \
                (ACC).w = fmaf(pj, cf.w, (ACC).w);                              \
            }                                                                   \
        }

    #define XREDUCE(ACC)                                                        \
        {                                                                       \
            _Pragma("unroll")                                                   \
            for (int off = 16; off < 64; off <<= 1) {                           \
                (ACC).x += __shfl_xor((ACC).x, off);                            \
                (ACC).y += __shfl_xor((ACC).y, off);                            \
                (ACC).z += __shfl_xor((ACC).z, off);                            \
                (ACC).w += __shfl_xor((ACC).w, off);                            \
            }                                                                   \
        }

    // ---- issue layer-1 AND layer-2 coeff slices up front (40 loads in flight) ----
    float4 c1[NF4], c2[NF4];
    #pragma unroll
    for (int j = 0; j < NF4; ++j) c1[j] = fA[j * 64];
    #pragma unroll
    for (int j = 0; j < NF4; ++j) c2[j] = fB[j * 64];

    // ================= layer 1: z = lift(x_last), no sigmoid =================
    float pv0 = tanhf((x0 - lc0) * lw0);
    float pv1 = ph1 ? tanhf((x1 - lc1) * lw1) : 0.0f;

    float4 a = make_float4(0.f, 0.f, 0.f, 0.f);
    CONTRACT(a, pv0, pv1, c1);          // waits only on c1's 20 loads

    // issue layer-3 slice (c1 registers are dead now)
    float4 c3[NF4];
    #pragma unroll
    for (int j = 0; j < NF4; ++j) c3[j] = fC[j * 64];

    XREDUCE(a);
    if (esub == 0) *(float4*)&part[w][og] = a;
    __syncthreads();
    if (t < DIN) {
        float s = 0.0f;
        #pragma unroll
        for (int ww = 0; ww < NW; ++ww) s += part[ww][t];
        act[t] = s;
    }
    __syncthreads();

    // ================= layer 2: h = sigmoid(rnn(z)) =================
    pv0 = tanhf((act[i0] - rc0) * rw0);
    pv1 = ph1 ? tanhf((act[i1] - rc1) * rw1) : 0.0f;

    a = make_float4(0.f, 0.f, 0.f, 0.f);
    CONTRACT(a, pv0, pv1, c2);
    XREDUCE(a);
    if (esub == 0) *(float4*)&part[w][og] = a;
    __syncthreads();
    if (t < DIN) {
        float s = 0.0f;
        #pragma unroll
        for (int ww = 0; ww < NW; ++ww) s += part[ww][t];
        act[t] = sigmoidf_(s);
    }
    __syncthreads();

    // ================= layer 3: phi = sigmoid(head(h)) + linear head =========
    pv0 = tanhf((act[i0] - hc0) * hw0);
    pv1 = ph1 ? tanhf((act[i1] - hc1) * hw1) : 0.0f;

    a = make_float4(0.f, 0.f, 0.f, 0.f);
    CONTRACT(a, pv0, pv1, c3);
    XREDUCE(a);
    if (esub == 0) *(float4*)&part[w][og] = a;
    __syncthreads();

    if (t < DIN) {   // wave 0 finishes in-register
        float s = 0.0f;
        #pragma unroll
        for (int ww = 0; ww < NW; ++ww) s += part[ww][t];
        s = sigmoidf_(s);
        float p0 = s * W0;
        float p1 = s * W1;
        #pragma unroll
        for (int off = 32; off > 0; off >>= 1) {
            p0 += __shfl_down(p0, off);
            p1 += __shfl_down(p1, off);
        }
        if (t == 0) {
            out[b * NCLS + 0] = p0 + bvec[0];
            out[b * NCLS + 1] = p1 + bvec[1];
        }
    }

    #undef CONTRACT
    #undef XREDUCE
}

extern "C" void kernel_launch(void* const* d_in, const int* in_sizes, int n_in,
                              void* d_out, int out_size, void* d_ws, size_t ws_size,
                              hipStream_t stream) {
    const float* x          = (const float*)d_in[0];
    const float* lift_c     = (const float*)d_in[1];
    const float* lift_w     = (const float*)d_in[2];
    const float* lift_coef  = (const float*)d_in[3];
    const float* rnn_c      = (const float*)d_in[4];
    const float* rnn_w      = (const float*)d_in[5];
    const float* rnn_coef   = (const float*)d_in[6];
    const float* head_c     = (const float*)d_in[7];
    const float* head_w     = (const float*)d_in[8];
    const float* head_coef  = (const float*)d_in[9];
    const float* W          = (const float*)d_in[10];
    const float* bvec       = (const float*)d_in[11];
    float* out              = (float*)d_out;

    kan_fwd<<<dim3(BB), dim3(NTHR), 0, stream>>>(
        x, lift_c, lift_w, lift_coef,
        rnn_c, rnn_w, rnn_coef,
        head_c, head_w, head_coef,
        W, bvec, out);
}

// Round 8
// 12.567 us; speedup vs baseline: 1.8604x; 1.0803x over previous
//
#include <hip/hip_runtime.h>
#include <math.h>

// B=256, T=512, D_IN=64, HID=64, NB=10, NCLS=2
// Output depends ONLY on x[:, T-1, :] (lift of other timesteps is dead code).
//
// Structure: 256 blocks (1 sample/CU) x 1024 threads (16 waves = 4/SIMD).
// 16 waves is the only config that saturates per-XCD L2 BW (R2 vs R6/R7
// evidence); the kernel floor is the 480 KB/CU coeff stream (~3.5 us).
// float4 coeff loads, phi in-register + shfl broadcast (no phi LDS phase),
// one-layer-ahead prefetch. VGPR budget: 2x40 (coeff slices) + ~30 misc < 128.
#define BB    256
#define TT    512
#define DIN   64
#define HIDD  64
#define NBAS  10
#define NCLS  2

#define NTHR  1024
#define NW    16
#define EPT   40                  // e-terms per wave (e = i*NB + k, 640 total)
#define NF4   10                  // float4 coeff loads per lane per layer

__device__ __forceinline__ float sigmoidf_(float v) {
    return 1.0f / (1.0f + expf(-v));
}

__global__ __launch_bounds__(NTHR) void kan_fwd(
    const float* __restrict__ x,
    const float* __restrict__ lift_c, const float* __restrict__ lift_w, const float* __restrict__ lift_coef,
    const float* __restrict__ rnn_c,  const float* __restrict__ rnn_w,  const float* __restrict__ rnn_coef,
    const float* __restrict__ head_c, const float* __restrict__ head_w, const float* __restrict__ head_coef,
    const float* __restrict__ W, const float* __restrict__ bvec,
    float* __restrict__ out)
{
    const int b    = blockIdx.x;      // sample
    const int t    = threadIdx.x;
    const int l    = t & 63;          // lane
    const int w    = t >> 6;          // wave 0..15 -> e-slice [40w, 40w+40)
    const int esub = l >> 4;          // 0..3
    const int og   = (l & 15) << 2;   // channel group: 0,4,...,60

    __shared__ float act[DIN];
    __shared__ __align__(16) float part[NW][DIN];

    // phi work: lane l<40 computes phi for e = 40w + l -> i = 4w + l/10, k = l%10
    const bool pl  = (l < EPT);
    const int  i0  = (w << 2) + l / NBAS;   // valid (<64) only when pl
    const int  k0  = l % NBAS;

    // layer-1 phi input straight from x (guarded: i0 OOB for l>=40)
    const float* xb = x + ((size_t)b * TT + (TT - 1)) * DIN;
    const float x0 = pl ? xb[i0] : 0.0f;

    float W0 = 0.0f, W1 = 0.0f;
    if (t < DIN) { W0 = W[t * NCLS + 0]; W1 = W[t * NCLS + 1]; }

    // coeff float4 base: element e = 40w+esub+4j, channels og..og+3;
    // float4 index = e*16 + og/4, j-stride 64 float4s. Same offset, 3 bases.
    const size_t fbase = (size_t)(EPT * w + esub) * 16 + (og >> 2);
    const float4* fA = (const float4*)lift_coef + fbase;
    const float4* fB = (const float4*)rnn_coef  + fbase;
    const float4* fC = (const float4*)head_coef + fbase;

    // term j needs phi local idx esub+4j (0..39) -> broadcast from lane esub+4j
    #define CONTRACT(ACC, PV, CARR)                                             \
        {                                                                       \
            _Pragma("unroll")                                                   \
            for (int j = 0; j < NF4; ++j) {                                     \
                const float pj = __shfl((PV), esub + 4 * j);                    \
                const float4 cf = (CARR)[j];                                    \
                (ACC).x = fmaf(pj, cf.x, (ACC).x);                              \
                (ACC).y = fmaf(pj, cf.y, (ACC).y);                              \
                (ACC).z = fmaf(pj, cf.z, (ACC).z);                              \
                (ACC).w = fmaf(pj, cf.w, (ACC).w);                              \
            }                                                                   \
        }

    #define XREDUCE(ACC)                                                        \
        {                                                                       \
            _Pragma("unroll")                                                   \
            for (int off = 16; off < 64; off <<= 1) {                           \
                (ACC).x += __shfl_xor((ACC).x, off);                            \
                (ACC).y += __shfl_xor((ACC).y, off);                            \
                (ACC).z += __shfl_xor((ACC).z, off);                            \
                (ACC).w += __shfl_xor((ACC).w, off);                            \
            }                                                                   \
        }

    // ---- layer-1 coeff slice (10 f4 = 40 VGPR) ----
    float4 c1[NF4];
    #pragma unroll
    for (int j = 0; j < NF4; ++j) c1[j] = fA[j * 64];

    // ================= layer 1: z = lift(x_last), no sigmoid =================
    float pv = pl ? tanhf((x0 - lift_c[k0]) / lift_w[k0]) : 0.0f;

    float4 a = make_float4(0.f, 0.f, 0.f, 0.f);
    CONTRACT(a, pv, c1);

    // prefetch layer-2 slice (c1 regs dead; covers XREDUCE+barriers+reduce)
    float4 c2[NF4];
    #pragma unroll
    for (int j = 0; j < NF4; ++j) c2[j] = fB[j * 64];

    XREDUCE(a);
    if (esub == 0) *(float4*)&part[w][og] = a;
    __syncthreads();
    if (t < DIN) {
        float s = 0.0f;
        #pragma unroll
        for (int ww = 0; ww < NW; ++ww) s += part[ww][t];
        act[t] = s;
    }
    __syncthreads();

    // ================= layer 2: h = sigmoid(rnn(z)) =================
    pv = pl ? tanhf((act[i0] - rnn_c[k0]) / rnn_w[k0]) : 0.0f;

    a = make_float4(0.f, 0.f, 0.f, 0.f);
    CONTRACT(a, pv, c2);

    // prefetch layer-3 slice (c2 regs dead)
    float4 c3[NF4];
    #pragma unroll
    for (int j = 0; j < NF4; ++j) c3[j] = fC[j * 64];

    XREDUCE(a);
    if (esub == 0) *(float4*)&part[w][og] = a;
    __syncthreads();
    if (t < DIN) {
        float s = 0.0f;
        #pragma unroll
        for (int ww = 0; ww < NW; ++ww) s += part[ww][t];
        act[t] = sigmoidf_(s);
    }
    __syncthreads();

    // ================= layer 3: phi = sigmoid(head(h)) + linear head =========
    pv = pl ? tanhf((act[i0] - head_c[k0]) / head_w[k0]) : 0.0f;

    a = make_float4(0.f, 0.f, 0.f, 0.f);
    CONTRACT(a, pv, c3);
    XREDUCE(a);
    if (esub == 0) *(float4*)&part[w][og] = a;
    __syncthreads();

    if (t < DIN) {   // wave 0 finishes in-register
        float s = 0.0f;
        #pragma unroll
        for (int ww = 0; ww < NW; ++ww) s += part[ww][t];
        s = sigmoidf_(s);
        float p0 = s * W0;
        float p1 = s * W1;
        #pragma unroll
        for (int off = 32; off > 0; off >>= 1) {
            p0 += __shfl_down(p0, off);
            p1 += __shfl_down(p1, off);
        }
        if (t == 0) {
            out[b * NCLS + 0] = p0 + bvec[0];
            out[b * NCLS + 1] = p1 + bvec[1];
        }
    }

    #undef CONTRACT
    #undef XREDUCE
}

extern "C" void kernel_launch(void* const* d_in, const int* in_sizes, int n_in,
                              void* d_out, int out_size, void* d_ws, size_t ws_size,
                              hipStream_t stream) {
    const float* x          = (const float*)d_in[0];
    const float* lift_c     = (const float*)d_in[1];
    const float* lift_w     = (const float*)d_in[2];
    const float* lift_coef  = (const float*)d_in[3];
    const float* rnn_c      = (const float*)d_in[4];
    const float* rnn_w      = (const float*)d_in[5];
    const float* rnn_coef   = (const float*)d_in[6];
    const float* head_c     = (const float*)d_in[7];
    const float* head_w     = (const float*)d_in[8];
    const float* head_coef  = (const float*)d_in[9];
    const float* W          = (const float*)d_in[10];
    const float* bvec       = (const float*)d_in[11];
    float* out              = (float*)d_out;

    kan_fwd<<<dim3(BB), dim3(NTHR), 0, stream>>>(
        x, lift_c, lift_w, lift_coef,
        rnn_c, rnn_w, rnn_coef,
        head_c, head_w, head_coef,
        W, bvec, out);
}